// Round 5
// baseline (230.941 us; speedup 1.0000x reference)
//
#include <hip/hip_runtime.h>
#include <stdint.h>
#include <math.h>

#define NPTS 4096      // N
#define NF 512         // feature dim
#define NBINS 16
#define BSZ 256        // bin size
#define TOPK 16
#define NBATCH 2
#define SPART (NBATCH * NBINS * BSZ * BSZ)   // 2,097,152 floats per K-quarter
#define SA 164         // swizzled LDS row stride (floats): max f(127)=155, pad to 164

typedef float vf4 __attribute__((ext_vector_type(4)));   // clang-native for nontemporal builtins

// intra-row LDS swizzle: insert 4 floats per 16 -> stride-8 segment reads become 2-way (free)
__device__ __forceinline__ int sw(int c) { return c + ((c >> 4) << 2); }

// ---------- kernel 1: LSH bin assignment (one wave per point) ----------
__global__ __launch_bounds__(256) void k_assign(const float* __restrict__ x,
                                                const float* __restrict__ cb,
                                                int* __restrict__ bin_idx) {
    int gw   = (blockIdx.x * 256 + threadIdx.x) >> 6;   // point id 0..8191
    int lane = threadIdx.x & 63;
    const float* row = x + (size_t)gw * NF;
    float acc[8];
#pragma unroll
    for (int j = 0; j < 8; j++) acc[j] = 0.f;
    for (int f = lane; f < NF; f += 64) {
        float xv = row[f];
        const float4* c = (const float4*)(cb + f * 16);
        float4 c0 = c[0], c1 = c[1];
        acc[0] += xv * c0.x; acc[1] += xv * c0.y; acc[2] += xv * c0.z; acc[3] += xv * c0.w;
        acc[4] += xv * c1.x; acc[5] += xv * c1.y; acc[6] += xv * c1.z; acc[7] += xv * c1.w;
    }
#pragma unroll
    for (int off = 32; off > 0; off >>= 1) {
#pragma unroll
        for (int j = 0; j < 8; j++) acc[j] += __shfl_xor(acc[j], off, 64);
    }
    if (lane == 0) {
        // argmax over [mul0..mul7, -mul0..-mul7], first max wins (strict >)
        float best = acc[0]; int bi = 0;
#pragma unroll
        for (int j = 1; j < 8; j++) { if (acc[j] > best) { best = acc[j]; bi = j; } }
#pragma unroll
        for (int j = 0; j < 8; j++) { float v = -acc[j]; if (v > best) { best = v; bi = 8 + j; } }
        bin_idx[gw] = bi;
    }
}

// ---------- kernel 2: stable counting sort, 32 blocks (one per batch x key) ----------
// Produces the identical stable argsort as the old 2-block version.
__global__ __launch_bounds__(256) void k_sort(const int* __restrict__ bin_idx,
                                              int* __restrict__ order) {
    __shared__ int s_eq[256];
    __shared__ int s_lt[256];
    int b   = blockIdx.x >> 4;
    int key = blockIdx.x & 15;
    int t   = threadIdx.x;
    const int* bi = bin_idx + b * NPTS;
    int base = t * 16;
    int e[16];
    { const int4* p = (const int4*)(bi + base);
      int4 a0 = p[0], a1 = p[1], a2 = p[2], a3 = p[3];
      e[0]=a0.x; e[1]=a0.y; e[2]=a0.z; e[3]=a0.w;
      e[4]=a1.x; e[5]=a1.y; e[6]=a1.z; e[7]=a1.w;
      e[8]=a2.x; e[9]=a2.y; e[10]=a2.z; e[11]=a2.w;
      e[12]=a3.x; e[13]=a3.y; e[14]=a3.z; e[15]=a3.w; }
    int ceq = 0, clt = 0;
#pragma unroll
    for (int i = 0; i < 16; i++) { ceq += (e[i] == key); clt += (e[i] < key); }
    s_eq[t] = ceq; s_lt[t] = clt;
    __syncthreads();
    int keybase = 0, myoff = 0;
    for (int u = 0; u < 256; u++) {           // broadcast reads; cheap for a 2 us kernel
        keybase += s_lt[u];
        if (u < t) myoff += s_eq[u];
    }
    int* ob = order + b * NPTS + keybase;
#pragma unroll
    for (int i = 0; i < 16; i++) {
        if (e[i] == key) ob[myoff++] = base + i;   // in index order => stable
    }
}

// ---------- kernel 3: per-bin Gram matrix, fp32, 128x128 tile, K split x4 ----------
// grid 512 = kh(4) x tn(2) x tm(2) x bin(16) x b(2); S partials in d_ws
// LDS fragment layout swizzled (sw) to kill the 4-way bank conflict on stride-8 reads.
__global__ __launch_bounds__(256, 2) void k_gemm(const float* __restrict__ x,
                                                 const int* __restrict__ order,
                                                 float* __restrict__ S) {
    int blk = blockIdx.x;
    int kh  = blk & 3;
    int tn  = (blk >> 2) & 1;
    int tm  = (blk >> 3) & 1;
    int bin = (blk >> 4) & 15;
    int b   = blk >> 8;
    int t  = threadIdx.x;
    int tx = t & 15, ty = t >> 4;
    __shared__ int   idxA[128];
    __shared__ int   idxB[128];
    __shared__ float Asl[32 * SA];   // k-major, swizzled
    __shared__ float Bsl[32 * SA];
    int ob = b * NPTS + bin * BSZ;
    if (t < 128) idxA[t] = order[ob + tm * 128 + t];
    else         idxB[t - 128] = order[ob + tn * 128 + (t - 128)];
    __syncthreads();
    const float* xb = x + (size_t)b * (NPTS * NF);
    int rowi = t & 127;
    int qb   = t >> 7;   // 0 or 1: which interleaved quad set this thread loads
    int swr  = sw(rowi);            // swizzled store column for staging
    int swA  = sw(ty * 8);          // swizzled read base (ty*8 and +4 stay in-group)
    int swB  = sw(tx * 8);
    const float* rowA = xb + (size_t)idxA[rowi] * NF + kh * 128;
    const float* rowB = xb + (size_t)idxB[rowi] * NF + kh * 128;
    float acc[8][8];
#pragma unroll
    for (int i = 0; i < 8; i++)
#pragma unroll
        for (int j = 0; j < 8; j++) acc[i][j] = 0.f;
    float4 pa[4], pb[4];
#pragma unroll
    for (int l = 0; l < 4; l++) {
        pa[l] = *(const float4*)(rowA + (qb + 2 * l) * 4);
        pb[l] = *(const float4*)(rowB + (qb + 2 * l) * 4);
    }
    for (int it = 0; it < 4; it++) {
        __syncthreads();
#pragma unroll
        for (int l = 0; l < 4; l++) {
            int kq = (qb + 2 * l) * 4;
            Asl[(kq + 0) * SA + swr] = pa[l].x; Asl[(kq + 1) * SA + swr] = pa[l].y;
            Asl[(kq + 2) * SA + swr] = pa[l].z; Asl[(kq + 3) * SA + swr] = pa[l].w;
            Bsl[(kq + 0) * SA + swr] = pb[l].x; Bsl[(kq + 1) * SA + swr] = pb[l].y;
            Bsl[(kq + 2) * SA + swr] = pb[l].z; Bsl[(kq + 3) * SA + swr] = pb[l].w;
        }
        __syncthreads();
        if (it < 3) {  // prefetch next K-chunk; latency hides under compute
            const float* a2 = rowA + (it + 1) * 32;
            const float* b2 = rowB + (it + 1) * 32;
#pragma unroll
            for (int l = 0; l < 4; l++) {
                pa[l] = *(const float4*)(a2 + (qb + 2 * l) * 4);
                pb[l] = *(const float4*)(b2 + (qb + 2 * l) * 4);
            }
        }
#pragma unroll
        for (int kk = 0; kk < 32; kk++) {
            float4 a0 = *(const float4*)&Asl[kk * SA + swA];
            float4 a1 = *(const float4*)&Asl[kk * SA + swA + 4];
            float4 b0 = *(const float4*)&Bsl[kk * SA + swB];
            float4 b1 = *(const float4*)&Bsl[kk * SA + swB + 4];
            float av[8] = {a0.x, a0.y, a0.z, a0.w, a1.x, a1.y, a1.z, a1.w};
            float bv[8] = {b0.x, b0.y, b0.z, b0.w, b1.x, b1.y, b1.z, b1.w};
#pragma unroll
            for (int i = 0; i < 8; i++)
#pragma unroll
                for (int j = 0; j < 8; j++) acc[i][j] += av[i] * bv[j];
        }
    }
    float* Sp = S + (size_t)kh * SPART;
    size_t rowbase = (size_t)(b * NBINS + bin) * BSZ;
#pragma unroll
    for (int i = 0; i < 8; i++) {
        int r = tm * 128 + ty * 8 + i;
        float* orow = Sp + (rowbase + r) * BSZ + tn * 128 + tx * 8;
        *(float4*)(orow)     = make_float4(acc[i][0], acc[i][1], acc[i][2], acc[i][3]);
        *(float4*)(orow + 4) = make_float4(acc[i][4], acc[i][5], acc[i][6], acc[i][7]);
    }
}

// ---------- kernel 4: fused exact top-16 + output-row write (one wave per bin-row) ----------
// j = 4*lane + c mapping: each S plane is one coalesced float4 load. Selection math is
// j-based and shuffle-max spans all 256 candidates, so results are identical.
__global__ __launch_bounds__(64) void k_topkw(const float* __restrict__ S,
                                              const int* __restrict__ order,
                                              float* __restrict__ out) {
    __shared__ float buf[NPTS];
    int row  = blockIdx.x;            // (b*16+bin)*256 + i
    int lane = threadIdx.x;           // 0..63
    const float* s0 = S + (size_t)row * BSZ;
    vf4 v0 = *(const vf4*)&s0[4 * lane];
    vf4 v1 = *(const vf4*)&s0[4 * lane + SPART];
    vf4 v2 = *(const vf4*)&s0[4 * lane + 2 * SPART];
    vf4 v3 = *(const vf4*)&s0[4 * lane + 3 * SPART];
    unsigned long long key[4];
#pragma unroll
    for (int c = 0; c < 4; c++) {
        int j = 4 * lane + c;
        float d = v0[c] + v1[c] + v2[c] + v3[c];     // same add order as before
        float v = 1.0f / (1.0f + expf(-d));          // sigmoid, saturates to 1.0f like ref
        key[c] = ((unsigned long long)__float_as_uint(v) << 32) | (unsigned)(255 - j);
    }
    int   wj[TOPK];
    float wv[TOPK];
#pragma unroll
    for (int it = 0; it < TOPK; it++) {
        unsigned long long k = key[0];
        if (key[1] > k) k = key[1];
        if (key[2] > k) k = key[2];
        if (key[3] > k) k = key[3];
#pragma unroll
        for (int off = 32; off > 0; off >>= 1) {
            unsigned long long o = __shfl_xor(k, off, 64);
            if (o > k) k = o;
        }
        int jw = 255 - (int)(k & 0xFFull);
        wj[it] = jw;                               // uniform across the wave
        wv[it] = __uint_as_float((unsigned)(k >> 32));
        if ((jw >> 2) == lane) {   // owner invalidates the winner
            int c = jw & 3;
            if      (c == 0) key[0] = 0ull;
            else if (c == 1) key[1] = 0ull;
            else if (c == 2) key[2] = 0ull;
            else             key[3] = 0ull;
        }
    }
    // zero the 16 KB row image in LDS
    vf4 z = {0.f, 0.f, 0.f, 0.f};
#pragma unroll
    for (int u = 0; u < 16; u++) ((vf4*)buf)[u * 64 + lane] = z;
    int b   = row >> 12;
    int bin = (row >> 8) & 15;
    int i   = row & 255;
    const int* obp = order + b * NPTS + bin * BSZ;
    int srcg = obp[i];                // uniform scalar load
    __syncthreads();
    // patch the 16 winners (lane `it` handles winner it; static reg indexing)
#pragma unroll
    for (int it = 0; it < TOPK; it++) {
        if (lane == it) buf[obp[wj[it]]] = wv[it];
    }
    __syncthreads();
    // stream the composed row to HBM, coalesced nontemporal float4
    vf4* orow = (vf4*)(out + ((size_t)b * NPTS + srcg) * NPTS);
#pragma unroll
    for (int u = 0; u < 16; u++) {
        __builtin_nontemporal_store(((const vf4*)buf)[u * 64 + lane], &orow[u * 64 + lane]);
    }
}

extern "C" void kernel_launch(void* const* d_in, const int* in_sizes, int n_in,
                              void* d_out, int out_size, void* d_ws, size_t ws_size,
                              hipStream_t stream) {
    const float* x  = (const float*)d_in[0];
    const float* cb = (const float*)d_in[1];
    float* out = (float*)d_out;
    // workspace layout (ws_size = 512 MiB per harness fill evidence; we use ~33.6 MB)
    int*   bin_idx = (int*)d_ws;                       // 8192 ints
    int*   order   = bin_idx + NBATCH * NPTS;          // 8192 ints
    float* S       = (float*)d_ws + 4 * NBATCH * NPTS; // 64 KB offset; 4*SPART floats = 33.5 MB

    k_assign<<<2048, 256, 0, stream>>>(x, cb, bin_idx);
    k_sort  <<<NBATCH * NBINS, 256, 0, stream>>>(bin_idx, order);
    k_gemm  <<<512, 256, 0, stream>>>(x, order, S);
    k_topkw <<<NBATCH * NPTS * NBINS / 16, 64, 0, stream>>>(S, order, out);  // 8192 waves
}

// Round 6
// 212.722 us; speedup vs baseline: 1.0856x; 1.0856x over previous
//
#include <hip/hip_runtime.h>
#include <stdint.h>
#include <math.h>

#define NPTS 4096      // N
#define NF 512         // feature dim
#define NBINS 16
#define BSZ 256        // bin size
#define TOPK 16
#define NBATCH 2
#define SPART (NBATCH * NBINS * BSZ * BSZ)   // 2,097,152 floats per K-quarter

typedef float vf4 __attribute__((ext_vector_type(4)));   // clang-native for nontemporal builtins

// ---------- kernel 1: LSH bin assignment (one wave per point) ----------
__global__ __launch_bounds__(256) void k_assign(const float* __restrict__ x,
                                                const float* __restrict__ cb,
                                                int* __restrict__ bin_idx) {
    int gw   = (blockIdx.x * 256 + threadIdx.x) >> 6;   // point id 0..8191
    int lane = threadIdx.x & 63;
    const float* row = x + (size_t)gw * NF;
    float acc[8];
#pragma unroll
    for (int j = 0; j < 8; j++) acc[j] = 0.f;
    for (int f = lane; f < NF; f += 64) {
        float xv = row[f];
        const float4* c = (const float4*)(cb + f * 16);
        float4 c0 = c[0], c1 = c[1];
        acc[0] += xv * c0.x; acc[1] += xv * c0.y; acc[2] += xv * c0.z; acc[3] += xv * c0.w;
        acc[4] += xv * c1.x; acc[5] += xv * c1.y; acc[6] += xv * c1.z; acc[7] += xv * c1.w;
    }
#pragma unroll
    for (int off = 32; off > 0; off >>= 1) {
#pragma unroll
        for (int j = 0; j < 8; j++) acc[j] += __shfl_xor(acc[j], off, 64);
    }
    if (lane == 0) {
        // argmax over [mul0..mul7, -mul0..-mul7], first max wins (strict >)
        float best = acc[0]; int bi = 0;
#pragma unroll
        for (int j = 1; j < 8; j++) { if (acc[j] > best) { best = acc[j]; bi = j; } }
#pragma unroll
        for (int j = 0; j < 8; j++) { float v = -acc[j]; if (v > best) { best = v; bi = 8 + j; } }
        bin_idx[gw] = bi;
    }
}

// ---------- kernel 2: stable counting sort, 32 blocks (one per batch x key) ----------
// Produces the identical stable argsort as the old 2-block version.
__global__ __launch_bounds__(256) void k_sort(const int* __restrict__ bin_idx,
                                              int* __restrict__ order) {
    __shared__ int s_eq[256];
    __shared__ int s_lt[256];
    int b   = blockIdx.x >> 4;
    int key = blockIdx.x & 15;
    int t   = threadIdx.x;
    const int* bi = bin_idx + b * NPTS;
    int base = t * 16;
    int e[16];
    { const int4* p = (const int4*)(bi + base);
      int4 a0 = p[0], a1 = p[1], a2 = p[2], a3 = p[3];
      e[0]=a0.x; e[1]=a0.y; e[2]=a0.z; e[3]=a0.w;
      e[4]=a1.x; e[5]=a1.y; e[6]=a1.z; e[7]=a1.w;
      e[8]=a2.x; e[9]=a2.y; e[10]=a2.z; e[11]=a2.w;
      e[12]=a3.x; e[13]=a3.y; e[14]=a3.z; e[15]=a3.w; }
    int ceq = 0, clt = 0;
#pragma unroll
    for (int i = 0; i < 16; i++) { ceq += (e[i] == key); clt += (e[i] < key); }
    s_eq[t] = ceq; s_lt[t] = clt;
    __syncthreads();
    int keybase = 0, myoff = 0;
    for (int u = 0; u < 256; u++) {           // broadcast reads; cheap for a 2 us kernel
        keybase += s_lt[u];
        if (u < t) myoff += s_eq[u];
    }
    int* ob = order + b * NPTS + keybase;
#pragma unroll
    for (int i = 0; i < 16; i++) {
        if (e[i] == key) ob[myoff++] = base + i;   // in index order => stable
    }
}

// ---------- kernel 3: per-bin Gram matrix, fp32, 128x128 tile, K split x4 ----------
// grid 512 = kh(4) x tn(2) x tm(2) x bin(16) x b(2); S partials in d_ws
// (R4 body — the R5 LDS swizzle regressed 23 us and is reverted)
__global__ __launch_bounds__(256, 2) void k_gemm(const float* __restrict__ x,
                                                 const int* __restrict__ order,
                                                 float* __restrict__ S) {
    int blk = blockIdx.x;
    int kh  = blk & 3;
    int tn  = (blk >> 2) & 1;
    int tm  = (blk >> 3) & 1;
    int bin = (blk >> 4) & 15;
    int b   = blk >> 8;
    int t  = threadIdx.x;
    int tx = t & 15, ty = t >> 4;
    __shared__ int   idxA[128];
    __shared__ int   idxB[128];
    __shared__ float Asl[32][132];   // k-major, padded
    __shared__ float Bsl[32][132];
    int ob = b * NPTS + bin * BSZ;
    if (t < 128) idxA[t] = order[ob + tm * 128 + t];
    else         idxB[t - 128] = order[ob + tn * 128 + (t - 128)];
    __syncthreads();
    const float* xb = x + (size_t)b * (NPTS * NF);
    int rowi = t & 127;
    int qb   = t >> 7;   // 0 or 1: which interleaved quad set this thread loads
    const float* rowA = xb + (size_t)idxA[rowi] * NF + kh * 128;
    const float* rowB = xb + (size_t)idxB[rowi] * NF + kh * 128;
    float acc[8][8];
#pragma unroll
    for (int i = 0; i < 8; i++)
#pragma unroll
        for (int j = 0; j < 8; j++) acc[i][j] = 0.f;
    float4 pa[4], pb[4];
#pragma unroll
    for (int l = 0; l < 4; l++) {
        pa[l] = *(const float4*)(rowA + (qb + 2 * l) * 4);
        pb[l] = *(const float4*)(rowB + (qb + 2 * l) * 4);
    }
    for (int it = 0; it < 4; it++) {
        __syncthreads();
#pragma unroll
        for (int l = 0; l < 4; l++) {
            int kq = (qb + 2 * l) * 4;
            Asl[kq + 0][rowi] = pa[l].x; Asl[kq + 1][rowi] = pa[l].y;
            Asl[kq + 2][rowi] = pa[l].z; Asl[kq + 3][rowi] = pa[l].w;
            Bsl[kq + 0][rowi] = pb[l].x; Bsl[kq + 1][rowi] = pb[l].y;
            Bsl[kq + 2][rowi] = pb[l].z; Bsl[kq + 3][rowi] = pb[l].w;
        }
        __syncthreads();
        if (it < 3) {  // prefetch next K-chunk; latency hides under compute
            const float* a2 = rowA + (it + 1) * 32;
            const float* b2 = rowB + (it + 1) * 32;
#pragma unroll
            for (int l = 0; l < 4; l++) {
                pa[l] = *(const float4*)(a2 + (qb + 2 * l) * 4);
                pb[l] = *(const float4*)(b2 + (qb + 2 * l) * 4);
            }
        }
#pragma unroll
        for (int kk = 0; kk < 32; kk++) {
            float4 a0 = *(const float4*)&Asl[kk][ty * 8];
            float4 a1 = *(const float4*)&Asl[kk][ty * 8 + 4];
            float4 b0 = *(const float4*)&Bsl[kk][tx * 8];
            float4 b1 = *(const float4*)&Bsl[kk][tx * 8 + 4];
            float av[8] = {a0.x, a0.y, a0.z, a0.w, a1.x, a1.y, a1.z, a1.w};
            float bv[8] = {b0.x, b0.y, b0.z, b0.w, b1.x, b1.y, b1.z, b1.w};
#pragma unroll
            for (int i = 0; i < 8; i++)
#pragma unroll
                for (int j = 0; j < 8; j++) acc[i][j] += av[i] * bv[j];
        }
    }
    float* Sp = S + (size_t)kh * SPART;
    size_t rowbase = (size_t)(b * NBINS + bin) * BSZ;
#pragma unroll
    for (int i = 0; i < 8; i++) {
        int r = tm * 128 + ty * 8 + i;
        float* orow = Sp + (rowbase + r) * BSZ + tn * 128 + tx * 8;
        *(float4*)(orow)     = make_float4(acc[i][0], acc[i][1], acc[i][2], acc[i][3]);
        *(float4*)(orow + 4) = make_float4(acc[i][4], acc[i][5], acc[i][6], acc[i][7]);
    }
}

// ---------- kernel 4: fused exact top-16 + output-row write (one wave per bin-row) ----------
// j = 4*lane + c mapping: each S plane is one coalesced float4 load. Selection math is
// j-based and shuffle-max spans all 256 candidates, so results are identical.
__global__ __launch_bounds__(64) void k_topkw(const float* __restrict__ S,
                                              const int* __restrict__ order,
                                              float* __restrict__ out) {
    __shared__ float buf[NPTS];
    int row  = blockIdx.x;            // (b*16+bin)*256 + i
    int lane = threadIdx.x;           // 0..63
    const float* s0 = S + (size_t)row * BSZ;
    vf4 v0 = *(const vf4*)&s0[4 * lane];
    vf4 v1 = *(const vf4*)&s0[4 * lane + SPART];
    vf4 v2 = *(const vf4*)&s0[4 * lane + 2 * SPART];
    vf4 v3 = *(const vf4*)&s0[4 * lane + 3 * SPART];
    unsigned long long key[4];
#pragma unroll
    for (int c = 0; c < 4; c++) {
        int j = 4 * lane + c;
        float d = v0[c] + v1[c] + v2[c] + v3[c];     // same add order as before
        float v = 1.0f / (1.0f + expf(-d));          // sigmoid, saturates to 1.0f like ref
        key[c] = ((unsigned long long)__float_as_uint(v) << 32) | (unsigned)(255 - j);
    }
    int   wj[TOPK];
    float wv[TOPK];
#pragma unroll
    for (int it = 0; it < TOPK; it++) {
        unsigned long long k = key[0];
        if (key[1] > k) k = key[1];
        if (key[2] > k) k = key[2];
        if (key[3] > k) k = key[3];
#pragma unroll
        for (int off = 32; off > 0; off >>= 1) {
            unsigned long long o = __shfl_xor(k, off, 64);
            if (o > k) k = o;
        }
        int jw = 255 - (int)(k & 0xFFull);
        wj[it] = jw;                               // uniform across the wave
        wv[it] = __uint_as_float((unsigned)(k >> 32));
        if ((jw >> 2) == lane) {   // owner invalidates the winner
            int c = jw & 3;
            if      (c == 0) key[0] = 0ull;
            else if (c == 1) key[1] = 0ull;
            else if (c == 2) key[2] = 0ull;
            else             key[3] = 0ull;
        }
    }
    // zero the 16 KB row image in LDS
    vf4 z = {0.f, 0.f, 0.f, 0.f};
#pragma unroll
    for (int u = 0; u < 16; u++) ((vf4*)buf)[u * 64 + lane] = z;
    int b   = row >> 12;
    int bin = (row >> 8) & 15;
    int i   = row & 255;
    const int* obp = order + b * NPTS + bin * BSZ;
    int srcg = obp[i];                // uniform scalar load
    __syncthreads();
    // patch the 16 winners (lane `it` handles winner it; static reg indexing)
#pragma unroll
    for (int it = 0; it < TOPK; it++) {
        if (lane == it) buf[obp[wj[it]]] = wv[it];
    }
    __syncthreads();
    // stream the composed row to HBM, coalesced nontemporal float4
    vf4* orow = (vf4*)(out + ((size_t)b * NPTS + srcg) * NPTS);
#pragma unroll
    for (int u = 0; u < 16; u++) {
        __builtin_nontemporal_store(((const vf4*)buf)[u * 64 + lane], &orow[u * 64 + lane]);
    }
}

extern "C" void kernel_launch(void* const* d_in, const int* in_sizes, int n_in,
                              void* d_out, int out_size, void* d_ws, size_t ws_size,
                              hipStream_t stream) {
    const float* x  = (const float*)d_in[0];
    const float* cb = (const float*)d_in[1];
    float* out = (float*)d_out;
    // workspace layout (ws_size = 512 MiB per harness fill evidence; we use ~33.6 MB)
    int*   bin_idx = (int*)d_ws;                       // 8192 ints
    int*   order   = bin_idx + NBATCH * NPTS;          // 8192 ints
    float* S       = (float*)d_ws + 4 * NBATCH * NPTS; // 64 KB offset; 4*SPART floats = 33.5 MB

    k_assign<<<2048, 256, 0, stream>>>(x, cb, bin_idx);
    k_sort  <<<NBATCH * NBINS, 256, 0, stream>>>(bin_idx, order);
    k_gemm  <<<512, 256, 0, stream>>>(x, order, S);
    k_topkw <<<NBATCH * NPTS * NBINS / 16, 64, 0, stream>>>(S, order, out);  // 8192 waves
}